// Round 17
// baseline (2390.096 us; speedup 1.0000x reference)
//
#include <hip/hip_runtime.h>
#include <hip/hip_bf16.h>

// ---------------------------------------------------------------------------
// Transformer encoder fwd: B=32, S=1024, D=768, L=4, H=1536, C=6
// bf16 MFMA GEMMs. FP16 residual. Output FLOAT32.
// R17 = R13/R16 base + 3-deep B ring -> mid-tile barrier removed (1 barrier
// per K-tile). Race ledger: stageB(t+2) writes buf (t+2)%3, bfr reads buf
// t%3 (disjoint in window); B(t) completion forced by tile t-1 boundary
// vmcnt(NI) + tile-end barrier; A ping-pong unchanged (tile-end barrier
// certifies ldaf(cur) reads via each wave's p3 lgkmcnt(0)). vmcnt ledger
// byte-identical to R13. LDS: BN=256 -> 160K, BN=192 -> 136K.
// ---------------------------------------------------------------------------

typedef float f32x4 __attribute__((ext_vector_type(4)));
typedef unsigned short u16x4 __attribute__((ext_vector_type(4)));
typedef unsigned short u16x8 __attribute__((ext_vector_type(8)));
typedef int   i32x4 __attribute__((ext_vector_type(4)));
typedef __bf16 bf16x8 __attribute__((ext_vector_type(8)));

#define NB  32
#define NS  1024
#define ND  768
#define NH  1536
#define NL  4
#define NM  (NB * NS)   // 32768 rows total

__device__ __forceinline__ unsigned short f2bf(float f) {
    unsigned u = __builtin_bit_cast(unsigned, f);
    unsigned r = (u + 0x7FFFu + ((u >> 16) & 1u)) >> 16;   // RNE
    return (unsigned short)r;
}
__device__ __forceinline__ float bf2f(unsigned short h) {
    return __builtin_bit_cast(float, (unsigned)h << 16);
}
__device__ __forceinline__ unsigned short f2h(float f) {
    _Float16 h = (_Float16)f;
    return __builtin_bit_cast(unsigned short, h);
}
__device__ __forceinline__ float h2f(unsigned short u) {
    _Float16 h = __builtin_bit_cast(_Float16, u);
    return (float)h;
}

__device__ __forceinline__ void gl_lds16(const void* g, void* l) {
    __builtin_amdgcn_global_load_lds(
        (const __attribute__((address_space(1))) unsigned int*)g,
        (__attribute__((address_space(3))) unsigned int*)l, 16, 0, 0);
}

// ---------------- embedding -> fp16 residual --------------------------------
__global__ void embed_kernel(const int* __restrict__ tok,
                             const float* __restrict__ emb,
                             const float* __restrict__ pos,
                             unsigned short* __restrict__ x) {
    const int row = blockIdx.x;
    const int c = threadIdx.x;                 // 192 threads, 4 elems each
    const int tk = tok[row];
    const int s = row & (NS - 1);
    f32x4 e = *(const f32x4*)(emb + (size_t)tk * ND + c * 4);
    f32x4 p = *(const f32x4*)(pos + (size_t)s * ND + c * 4);
    u16x4 o;
    #pragma unroll
    for (int i = 0; i < 4; i++) o[i] = f2h(e[i] + p[i]);
    *(u16x4*)(x + (size_t)row * ND + c * 4) = o;
}

// ---------------- weight fp32 [R][C] -> bf16 transposed [C][R], z-strided ---
__global__ __launch_bounds__(256)
void wt_kernel(const float* __restrict__ in, unsigned short* __restrict__ out,
               int R, int Cc, size_t ozs) {
    __shared__ float ls[64][65];
    const int t = threadIdx.x;
    const size_t zi = (size_t)blockIdx.z * R * Cc;
    const size_t zo = (size_t)blockIdx.z * ozs;
    const int r0 = blockIdx.y * 64, c0 = blockIdx.x * 64;
    #pragma unroll
    for (int i = 0; i < 4; i++) {
        const int r = i * 16 + (t >> 4);
        const int c = (t & 15) * 4;
        f32x4 v = *(const f32x4*)(in + zi + (size_t)(r0 + r) * Cc + c0 + c);
        ls[r][c] = v[0]; ls[r][c + 1] = v[1]; ls[r][c + 2] = v[2]; ls[r][c + 3] = v[3];
    }
    __syncthreads();
    #pragma unroll
    for (int i = 0; i < 2; i++) {
        const int c = i * 32 + (t >> 3);
        const int r = (t & 7) * 8;
        u16x8 o;
        #pragma unroll
        for (int j = 0; j < 8; j++) o[j] = f2bf(ls[r + j][c]);
        *(u16x8*)(out + zo + (size_t)(c0 + c) * R + r0 + r) = o;
    }
}

// ---------------- concat bias [bq|bk] per layer -----------------------------
__global__ void bcat_kernel(const float* __restrict__ bq, const float* __restrict__ bk,
                            float* __restrict__ bqk) {
    const int i = blockIdx.x * 256 + threadIdx.x;       // NL*1536
    const int l = i / NH, j = i % NH;
    bqk[i] = (j < ND) ? bq[l * ND + j] : bk[l * ND + j - ND];
}

// ---------------- LayerNorm fp16 in -> bf16 out, one wave per row -----------
__global__ __launch_bounds__(256)
void ln_kernel(const unsigned short* __restrict__ x, const float* __restrict__ g,
               const float* __restrict__ bta, unsigned short* __restrict__ out) {
    const int row = blockIdx.x * 4 + (threadIdx.x >> 6);
    const int l = threadIdx.x & 63;
    const unsigned short* xr = x + (size_t)row * ND;
    f32x4 vv[3];
    float s = 0.f, ss = 0.f;
    #pragma unroll
    for (int j = 0; j < 3; j++) {
        u16x4 hv = *(const u16x4*)(xr + (j * 64 + l) * 4);
        #pragma unroll
        for (int i = 0; i < 4; i++) {
            vv[j][i] = h2f(hv[i]);
            s += vv[j][i]; ss += vv[j][i] * vv[j][i];
        }
    }
    #pragma unroll
    for (int off = 32; off >= 1; off >>= 1) {
        s += __shfl_xor(s, off); ss += __shfl_xor(ss, off);
    }
    const float mean = s * (1.0f / ND);
    const float var = ss * (1.0f / ND) - mean * mean;
    const float rstd = rsqrtf(var + 1e-5f);
    #pragma unroll
    for (int j = 0; j < 3; j++) {
        const int c = (j * 64 + l) * 4;
        f32x4 gv = *(const f32x4*)(g + c);
        f32x4 bv = *(const f32x4*)(bta + c);
        u16x4 o;
        #pragma unroll
        for (int i = 0; i < 4; i++) o[i] = f2bf((vv[j][i] - mean) * rstd * gv[i] + bv[i]);
        *(u16x4*)(out + (size_t)row * ND + c) = o;
    }
}

// ---------------- GEMM 256xBN, 8-phase, 1-barrier, B-ring: C = A @ Bt^T -----
// 512 threads = 8 waves (2M x 4N), per-wave 128x(BN/4) out, BK=64.
// LDS: A dbuf 2x32K @0; B ring 3x(BN*128) @64K. Stage chunk = 8KB (64 rows).
// Tile t: A(t+1)@p0/p1 (buf (t+1)&1), B(t+2)@p2/p3 (buf (t+2)%3);
// boundary vmcnt(NI); ONE tile-end barrier. T2 both-sides XOR swizzle.
// EPI: 0 = scale+bias -> bf16; 1 = relu(bias+v) -> bf16; 2 = FP16 C += v
// BROW: bias indexed by output ROW m (for the V^T-producing GEMM).
template<int EPI, int BROW, int BN>
__device__ __forceinline__ void gemm_body(
        const unsigned short* __restrict__ A,
        const unsigned short* __restrict__ Bt,
        const float* __restrict__ bias,
        void* __restrict__ Cv,
        int N, int K, int lda, int ldb,
        long sA, long sB, long sC, float scale, int doswz) {
    constexpr int NI = BN / 64;                // B frags per wave / stage chunks
    constexpr unsigned BBYT = (unsigned)BN * 128u;
    __shared__ __align__(16) unsigned char lds[65536 + 3 * BN * 128];
    const int tid = threadIdx.x;
    const int wid = tid >> 6, l = tid & 63;
    const int wr = wid >> 2, wc = wid & 3;     // wave -> 2x4 grid
    const int fr = l & 15, fq = l >> 4;

    int bn = blockIdx.x, bm = blockIdx.y, bz = blockIdx.z;
    if (doswz) {                               // T1: XCD remap over full grid
        const int gx = gridDim.x, gy = gridDim.y;
        const int nwg = gx * gy * gridDim.z;
        const int flat = (bz * gy + bm) * gx + bn;
        int s = (flat & 7) * (nwg >> 3) + (flat >> 3);
        bn = s % gx; s /= gx; bm = s % gy; bz = s / gy;
    }

    const unsigned short* Ab = A + (size_t)bz * sA + (size_t)(bm * 256) * lda;
    const unsigned short* Bb = Bt + (size_t)bz * sB + (size_t)(bn * BN) * ldb;

    const int srow = tid >> 3;                           // 0..63
    const int scol = ((tid & 7) ^ (srow & 7)) * 8;       // elems (pre-swizzled)
    const unsigned ldst = (unsigned)wid * 1024u;         // wave base (bytes)

    auto stageA = [&](int kt, int h) {                   // 2 insts (128 rows)
        const unsigned base = (unsigned)(kt & 1) * 32768u + (unsigned)h * 16384u;
        #pragma unroll
        for (int li = 0; li < 2; li++)
            gl_lds16(Ab + (size_t)(h * 128 + li * 64 + srow) * lda + (kt * 64 + scol),
                     lds + base + (unsigned)li * 8192u + ldst);
    };
    auto stageB1 = [&](int kt, int li) {                 // 1 inst (64 rows)
        const unsigned base = 65536u + (unsigned)(kt % 3) * BBYT;
        gl_lds16(Bb + (size_t)(li * 64 + srow) * ldb + (kt * 64 + scol),
                 lds + base + (unsigned)li * 8192u + ldst);
    };
    auto ldaf = [&](int buf, int mi, int kk) -> bf16x8 {
        const unsigned r = (unsigned)(wr * 128 + mi * 16 + fr);
        unsigned byt = r * 128u + (unsigned)kk * 64u + (unsigned)fq * 16u;
        byt ^= (r & 7u) << 4;
        return *(const bf16x8*)(lds + (unsigned)buf * 32768u + byt);
    };
    auto ldbf = [&](int buf, int ni, int kk) -> bf16x8 {
        const unsigned r = (unsigned)(wc * (BN / 4) + ni * 16 + fr);
        unsigned byt = r * 128u + (unsigned)kk * 64u + (unsigned)fq * 16u;
        byt ^= (r & 7u) << 4;
        return *(const bf16x8*)(lds + 65536u + (unsigned)buf * BBYT + byt);
    };

    const int NT = K >> 6;
    f32x4 acc[8][NI] = {};

    // ---- prologue: B(0)->ring0, A(0), B(1)->ring1; wait B(0)+A(0) ----------
    #pragma unroll
    for (int li = 0; li < NI; li++) stageB1(0, li);
    stageA(0, 0); stageA(0, 1);
    #pragma unroll
    for (int li = 0; li < NI; li++) stageB1(1, li);
    if constexpr (NI == 4)      asm volatile("s_waitcnt vmcnt(4)" ::: "memory");
    else if constexpr (NI == 3) asm volatile("s_waitcnt vmcnt(3)" ::: "memory");
    else                        asm volatile("s_waitcnt vmcnt(2)" ::: "memory");
    __builtin_amdgcn_s_barrier();
    __builtin_amdgcn_sched_barrier(0);

    int bRd = 0;                               // B ring read index = t % 3
    for (int t = 0; t < NT; ++t) {
        const int cur = t & 1;
        bf16x8 bfr[2 * NI];                    // B-frags, live all 4 phases
        #pragma unroll
        for (int ni = 0; ni < NI; ni++) {
            bfr[ni * 2 + 0] = ldbf(bRd, ni, 0);
            bfr[ni * 2 + 1] = ldbf(bRd, ni, 1);
        }
        #pragma unroll
        for (int p = 0; p < 4; p++) {
            bf16x8 a0 = ldaf(cur, 2 * p,     0);
            bf16x8 a1 = ldaf(cur, 2 * p,     1);
            bf16x8 a2 = ldaf(cur, 2 * p + 1, 0);
            bf16x8 a3 = ldaf(cur, 2 * p + 1, 1);
            if (p < 2) { if (t + 1 < NT) stageA(t + 1, p); }
            else if (p == 2) {
                if (t + 2 < NT) { stageB1(t + 2, 0); stageB1(t + 2, 1); }
            } else {
                if (t + 2 < NT) {
                    #pragma unroll
                    for (int li = 2; li < NI; li++) stageB1(t + 2, li);
                }
            }
            if (p == 3) {                      // boundary: B(t+2) insts fly
                if (t + 2 < NT) {
                    if constexpr (NI == 4)      asm volatile("s_waitcnt vmcnt(4)" ::: "memory");
                    else if constexpr (NI == 3) asm volatile("s_waitcnt vmcnt(3)" ::: "memory");
                    else                        asm volatile("s_waitcnt vmcnt(2)" ::: "memory");
                } else {
                    asm volatile("s_waitcnt vmcnt(0)" ::: "memory");
                }
            }
            asm volatile("s_waitcnt lgkmcnt(0)" ::: "memory");
            __builtin_amdgcn_sched_barrier(0);
            __builtin_amdgcn_s_setprio(1);
            #pragma unroll
            for (int ni = 0; ni < NI; ni++) {
                acc[2 * p][ni] = __builtin_amdgcn_mfma_f32_16x16x32_bf16(
                    a0, bfr[ni * 2 + 0], acc[2 * p][ni], 0, 0, 0);
                acc[2 * p][ni] = __builtin_amdgcn_mfma_f32_16x16x32_bf16(
                    a1, bfr[ni * 2 + 1], acc[2 * p][ni], 0, 0, 0);
                acc[2 * p + 1][ni] = __builtin_amdgcn_mfma_f32_16x16x32_bf16(
                    a2, bfr[ni * 2 + 0], acc[2 * p + 1][ni], 0, 0, 0);
                acc[2 * p + 1][ni] = __builtin_amdgcn_mfma_f32_16x16x32_bf16(
                    a3, bfr[ni * 2 + 1], acc[2 * p + 1][ni], 0, 0, 0);
            }
            __builtin_amdgcn_s_setprio(0);
            __builtin_amdgcn_sched_barrier(0);
            if (p == 3) {                      // single tile-end barrier:
                __builtin_amdgcn_s_barrier();  // all waves' ds_reads of this
                __builtin_amdgcn_sched_barrier(0); // tile done (p3 lgkmcnt(0))
            }
        }
        bRd = (bRd == 2) ? 0 : bRd + 1;
    }

    // ---- epilogue: LDS-bounce, conflict-free read, coalesced stores --------
    constexpr int WS = BN / 4;                  // wave col-span
    constexpr unsigned RST = (unsigned)BN * 4;  // bounce row stride (bytes)
    constexpr int CPR = BN / 64;                // 16-chunk groups per row
    const int erow = tid >> 4;                  // 0..31 (fixed per quarter-wave)
    const int echk = tid & 15;                  // 16B-chunk base within row
    #pragma unroll
    for (int h2 = 0; h2 < 2; ++h2) {
        __builtin_amdgcn_s_barrier();           // K-loop done / prev pass read
        if (wr == h2) {                         // this half's acc -> LDS fp32
            #pragma unroll
            for (int mi = 0; mi < 8; mi++) {
                #pragma unroll
                for (int ni = 0; ni < NI; ni++) {
                    const int nl = wc * WS + ni * 16 + fr;      // block-local col
                    const float bcol = (!BROW && bias) ? bias[bn * BN + nl] : 0.0f;
                    f32x4 brow = {0, 0, 0, 0};
                    if (BROW) brow = *(const f32x4*)(bias + bm * 256 + h2 * 128 + mi * 16 + fq * 4);
                    #pragma unroll
                    for (int r = 0; r < 4; r++) {
                        const int lm = mi * 16 + fq * 4 + r;    // 0..127
                        float v = acc[mi][ni][r] * scale + (BROW ? brow[r] : bcol);
                        if (EPI == 1) v = fmaxf(v, 0.0f);
                        const unsigned byt = ((unsigned)lm * RST + (unsigned)nl * 4u)
                                             ^ ((unsigned)(lm & 7) << 4);
                        *(float*)(lds + byt) = v;
                    }
                }
            }
        }
        __builtin_amdgcn_s_barrier();
        #pragma unroll
        for (int j = 0; j < 4 * CPR; j++) {
            const int row = erow + 32 * (j / CPR);              // 0..127
            const int c   = echk + 16 * (j % CPR);              // chunk idx
            const unsigned byt = ((unsigned)row * RST + (unsigned)c * 16u)
                                 ^ ((unsigned)(row & 7) << 4);
            f32x4 v = *(const f32x4*)(lds + byt);
            const int m = bm * 256 + h2 * 128 + row;
            const int ncol = bn * BN + c * 4;
            const size_t offc = (size_t)bz * sC + (size_t)m * N + ncol;
            if (EPI == 2) {                     // fp16 residual RMW
                unsigned short* cp = (unsigned short*)Cv + offc;
                u16x4 hv = *(const u16x4*)cp;
                u16x4 o;
                #pragma unroll
                for (int r = 0; r < 4; r++) o[r] = f2h(h2f(hv[r]) + v[r]);
                *(u16x4*)cp = o;
            } else {
                u16x4 o;
                o[0] = f2bf(v[0]); o[1] = f2bf(v[1]); o[2] = f2bf(v[2]); o[3] = f2bf(v[3]);
                *(u16x4*)((unsigned short*)Cv + offc) = o;
            }
        }
    }
}

#define GEMM_ARGS const unsigned short* A, const unsigned short* Bt, \
                  const float* bias, void* Cv, int N, int K, int lda, int ldb, \
                  long sA, long sB, long sC, float scale, int doswz
#define GEMM_PASS A, Bt, bias, Cv, N, K, lda, ldb, sA, sB, sC, scale, doswz

// named wrappers for exact rocprof attribution
__global__ __launch_bounds__(512, 2) void gemm_qkv_k (GEMM_ARGS) { gemm_body<0, 0, 256>(GEMM_PASS); }
__global__ __launch_bounds__(512, 2) void gemm_vt_k  (GEMM_ARGS) { gemm_body<0, 1, 256>(GEMM_PASS); }
__global__ __launch_bounds__(512, 2) void gemm_qk_k  (GEMM_ARGS) { gemm_body<0, 0, 256>(GEMM_PASS); }
__global__ __launch_bounds__(512, 2) void gemm_pv_k  (GEMM_ARGS) { gemm_body<2, 0, 192>(GEMM_PASS); }
__global__ __launch_bounds__(512, 2) void gemm_ffn1_k(GEMM_ARGS) { gemm_body<1, 0, 256>(GEMM_PASS); }
__global__ __launch_bounds__(512, 2) void gemm_ffn2_k(GEMM_ARGS) { gemm_body<2, 0, 192>(GEMM_PASS); }

// ---------------- masked softmax (mask from tokens), group-local ------------
__global__ __launch_bounds__(256)
void softmax_kernel(unsigned short* __restrict__ sc, const int* __restrict__ tokg) {
    const int row = blockIdx.x * 4 + (threadIdx.x >> 6);   // row in [0, G*NS)
    const int l = threadIdx.x & 63;
    const int b = row >> 10;                               // batch local to group
    unsigned short* rp = sc + (size_t)row * NS;
    const int* trow = tokg + (size_t)b * NS;
    float v[16];
    float mx = -3.4e38f;
    #pragma unroll
    for (int j = 0; j < 2; j++) {
        u16x8 u = *(const u16x8*)(rp + j * 512 + l * 8);
        i32x4 t0 = *(const i32x4*)(trow + j * 512 + l * 8);
        i32x4 t1 = *(const i32x4*)(trow + j * 512 + l * 8 + 4);
        #pragma unroll
        for (int i = 0; i < 8; i++) {
            const int tk = (i < 4) ? t0[i] : t1[i - 4];
            const float s = (tk == 0) ? -__builtin_inff() : bf2f(u[i]);
            v[j * 8 + i] = s;
            mx = fmaxf(mx, s);
        }
    }
    #pragma unroll
    for (int off = 32; off >= 1; off >>= 1) mx = fmaxf(mx, __shfl_xor(mx, off));
    float sum = 0.f;
    #pragma unroll
    for (int i = 0; i < 16; i++) { v[i] = __expf(v[i] - mx); sum += v[i]; }
    #pragma unroll
    for (int off = 32; off >= 1; off >>= 1) sum += __shfl_xor(sum, off);
    const float inv = 1.0f / sum;
    #pragma unroll
    for (int j = 0; j < 2; j++) {
        u16x8 o;
        #pragma unroll
        for (int i = 0; i < 8; i++) o[i] = f2bf(v[j * 8 + i] * inv);
        *(u16x8*)(rp + j * 512 + l * 8) = o;
    }
}

// ---------------- pool stage 1: partial masked sums over 128-row chunks -----
__global__ __launch_bounds__(256)
void pool1_kernel(const unsigned short* __restrict__ ln,
                  const int* __restrict__ tokg,
                  float* __restrict__ part, float* __restrict__ cnts,
                  int gbase) {                     // gbase: global batch offset
    const int d = blockIdx.x * 256 + threadIdx.x;  // 0..767
    const int b = blockIdx.y;                      // local batch
    const int z = blockIdx.z;                      // seq chunk 0..7
    float s = 0.f, cnt = 0.f;
    const int i0 = z * 128;
    for (int i = i0; i < i0 + 128; i++) {
        const int tk = tokg[b * NS + i];
        if (tk != 0) { s += bf2f(ln[((size_t)b * NS + i) * ND + d]); cnt += 1.0f; }
    }
    part[((size_t)z * NB + (gbase + b)) * ND + d] = s;
    if (d == 0) cnts[z * NB + (gbase + b)] = cnt;
}

// ---------------- pool stage 2: finalize -----------------------------------
__global__ __launch_bounds__(256)
void pool2_kernel(const float* __restrict__ part, const float* __restrict__ cnts,
                  float* __restrict__ pooled) {
    const int d = blockIdx.x * 256 + threadIdx.x;
    const int b = blockIdx.y;                      // global batch
    float s = 0.f, cnt = 0.f;
    #pragma unroll
    for (int z = 0; z < 8; z++) {
        s += part[((size_t)z * NB + b) * ND + d];
        cnt += cnts[z * NB + b];
    }
    pooled[(size_t)b * ND + d] = s / fmaxf(cnt, 1.0f);
}

// ---------------- classifier -> FLOAT32 output ------------------------------
__global__ void cls_kernel(const float* __restrict__ pooled, const float* __restrict__ wc,
                           const float* __restrict__ bc, float* __restrict__ out) {
    const int b = blockIdx.x;
    const int l = threadIdx.x;                  // 64 threads
    float a[6] = {0, 0, 0, 0, 0, 0};
    for (int d = l; d < ND; d += 64) {
        const float p = pooled[b * ND + d];
        #pragma unroll
        for (int c = 0; c < 6; c++) a[c] += p * wc[d * 6 + c];
    }
    #pragma unroll
    for (int c = 0; c < 6; c++) {
        #pragma unroll
        for (int off = 32; off >= 1; off >>= 1) a[c] += __shfl_xor(a[c], off);
    }
    if (l == 0) {
        #pragma unroll
        for (int c = 0; c < 6; c++) out[b * 6 + c] = a[c] + bc[c];
    }
}

__global__ void zero_out_kernel(float* out, int nel) {
    const int i = blockIdx.x * 256 + threadIdx.x;
    if (i < nel) out[i] = 0.0f;
}

// ---------------------------------------------------------------------------
extern "C" void kernel_launch(void* const* d_in, const int* in_sizes, int n_in,
                              void* d_out, int out_size, void* d_ws, size_t ws_size,
                              hipStream_t stream) {
    const int*   tok  = (const int*)d_in[0];
    const float* emb  = (const float*)d_in[1];
    const float* pos  = (const float*)d_in[2];
    const float* ln1w = (const float*)d_in[3];
    const float* ln1b = (const float*)d_in[4];
    const float* ln2w = (const float*)d_in[5];
    const float* ln2b = (const float*)d_in[6];
    const float* wq   = (const float*)d_in[7];
    const float* bq   = (const float*)d_in[8];
    const float* wk   = (const float*)d_in[9];
    const float* bk   = (const float*)d_in[10];
    const float* wv   = (const float*)d_in[11];
    const float* bv   = (const float*)d_in[12];
    const float* w1   = (const float*)d_in[13];
    const float* b1   = (const float*)d_in[14];
    const float* w2   = (const float*)d_in[15];
    const float* b2   = (const float*)d_in[16];
    const float* lnfw = (const float*)d_in[17];
    const float* lnfb = (const float*)d_in[18];
    const float* wcw  = (const float*)d_in[19];
    const float* bcb  = (const float*)d_in[20];
    float* out = (float*)d_out;                 // FLOAT32 output (ref dtype)

    // ---- fixed workspace carve-up ----
    size_t off = 0;
    auto carve = [&](size_t bytes) -> char* {
        char* p = (char*)d_ws + off;
        off += (bytes + 255) & ~(size_t)255;
        return p;
    };
    unsigned short* x = (unsigned short*)carve((size_t)NM * ND * 2);   // fp16 residual
    unsigned short* wqkT = (unsigned short*)carve((size_t)NL * NH * ND * 2); // [l][1536][768]
    unsigned short* wvT  = (unsigned short*)carve((size_t)NL * ND * ND * 2);
    unsigned short* w1T  = (unsigned short*)carve((size_t)NL * ND * NH * 2);
    unsigned short* w2T  = (unsigned short*)carve((size_t)NL * NH * ND * 2);
    float* bqk    = (float*)carve((size_t)NL * NH * 4);
    float* part   = (float*)carve((size_t)8 * NB * ND * 4);
    float* cnts   = (float*)carve((size_t)8 * NB * 4);
    float* pooled = (float*)carve((size_t)NB * ND * 4);

    // ---- adaptive group size ----
    int G = 32;
    while (G >= 1) {
        const size_t pool = (size_t)G *
            ((size_t)NS * ND * 2      // n
           + (size_t)NS * NH * 2      // qk (aliased by h)
           + (size_t)NS * ND * 2      // vt
           + (size_t)NS * NS * 2);    // sc
        if (off + pool <= ws_size) break;
        G >>= 1;
    }
    if (G < 1) {
        zero_out_kernel<<<(out_size + 255) / 256, 256, 0, stream>>>(out, out_size);
        return;
    }
    const int MG = G * NS;                       // rows per group
    unsigned short* n  = (unsigned short*)carve((size_t)MG * ND * 2);
    unsigned short* qk = (unsigned short*)carve((size_t)MG * NH * 2);
    unsigned short* vt = (unsigned short*)carve((size_t)MG * ND * 2); // [b][768][1024]
    unsigned short* sc = (unsigned short*)carve((size_t)G * NS * NS * 2);
    unsigned short* h  = qk;                     // alias: qk dead after scores

    // ---- prepass ----
    embed_kernel<<<NM, 192, 0, stream>>>(tok, emb, pos, x);
    wt_kernel<<<dim3(12, 12, NL), 256, 0, stream>>>(wq, wqkT,            ND, ND, (size_t)NH * ND);
    wt_kernel<<<dim3(12, 12, NL), 256, 0, stream>>>(wk, wqkT + ND * ND,  ND, ND, (size_t)NH * ND);
    wt_kernel<<<dim3(12, 12, NL), 256, 0, stream>>>(wv, wvT,             ND, ND, (size_t)ND * ND);
    wt_kernel<<<dim3(24, 12, NL), 256, 0, stream>>>(w1, w1T,             ND, NH, (size_t)ND * NH);
    wt_kernel<<<dim3(12, 24, NL), 256, 0, stream>>>(w2, w2T,             NH, ND, (size_t)NH * ND);
    bcat_kernel<<<NL * NH / 256, 256, 0, stream>>>(bq, bk, bqk);

    const float iscale = 1.0f / sqrtf((float)ND);
    const int NGroups = NB / G;
    const int MT = MG / 256;                     // 256-row tiles (=4G)
    for (int l = 0; l < NL; l++) {
        for (int g = 0; g < NGroups; g++) {
            const size_t rowoff = (size_t)g * MG;
            unsigned short* xg = x + rowoff * ND;
            ln_kernel<<<MG / 4, 256, 0, stream>>>(xg, ln1w + l * ND, ln1b + l * ND, n);
            // QK fused: qk[MG][1536] = n @ [wq|wk]^T + [bq|bk]   (6,MT)=768
            gemm_qkv_k<<<dim3(6, MT, 1), 512, 0, stream>>>(
                n, wqkT + (size_t)l * NH * ND, bqk + l * NH, qk,
                NH, ND, ND, ND, 0, 0, 0, 1.0f, ((6 * MT) % 8 == 0) ? 1 : 0);
            // V^T direct: vt[b][d][s]  (4,3,G)=384
            gemm_vt_k<<<dim3(4, 3, G), 512, 0, stream>>>(
                wvT + (size_t)l * ND * ND, n, bv + l * ND, vt,
                NS, ND, ND, ND, 0, (long)NS * ND, (long)ND * NS, 1.0f,
                ((12 * G) % 8 == 0) ? 1 : 0);
            // scores = q @ k^T * iscale   (4,4,G)=512
            gemm_qk_k<<<dim3(4, 4, G), 512, 0, stream>>>(
                qk, qk + ND, nullptr, sc,
                NS, ND, NH, NH, (long)NS * NH, (long)NS * NH, (long)NS * NS, iscale,
                ((16 * G) % 8 == 0) ? 1 : 0);
            softmax_kernel<<<MG / 4, 256, 0, stream>>>(sc, tok + rowoff);
            // x += attn @ V   (BN=192: (4,4,G)=512 = 2.0 rounds)
            gemm_pv_k<<<dim3(4, 4, G), 512, 0, stream>>>(
                sc, vt, nullptr, xg,
                ND, NS, NS, NS, (long)NS * NS, (long)ND * NS, (long)NS * ND, 1.0f,
                ((16 * G) % 8 == 0) ? 1 : 0);
            ln_kernel<<<MG / 4, 256, 0, stream>>>(xg, ln2w + l * ND, ln2b + l * ND, n);
            // FFN1 (6,MT)=768
            gemm_ffn1_k<<<dim3(6, MT, 1), 512, 0, stream>>>(
                n, w1T + (size_t)l * ND * NH, b1 + l * NH, h,
                NH, ND, ND, ND, 0, 0, 0, 1.0f, ((6 * MT) % 8 == 0) ? 1 : 0);
            // FFN2 (BN=192: (4,MT)=512 = 2.0 rounds)
            gemm_ffn2_k<<<dim3(4, MT, 1), 512, 0, stream>>>(
                h, w2T + (size_t)l * ND * NH, b2 + l * ND, xg,
                ND, NH, NH, NH, 0, 0, 0, 1.0f, ((4 * MT) % 8 == 0) ? 1 : 0);
        }
    }
    for (int g = 0; g < NGroups; g++) {
        const size_t rowoff = (size_t)g * MG;
        ln_kernel<<<MG / 4, 256, 0, stream>>>(x + rowoff * ND, lnfw, lnfb, n);
        pool1_kernel<<<dim3(3, G, 8), 256, 0, stream>>>(n, tok + rowoff, part, cnts, g * G);
    }
    pool2_kernel<<<dim3(3, NB), 256, 0, stream>>>(part, cnts, pooled);
    cls_kernel<<<NB, 64, 0, stream>>>(pooled, wcw, bcb, out);
}

// Round 18
// 2368.346 us; speedup vs baseline: 1.0092x; 1.0092x over previous
//
#include <hip/hip_runtime.h>
#include <hip/hip_bf16.h>

// ---------------------------------------------------------------------------
// Transformer encoder fwd: B=32, S=1024, D=768, L=4, H=1536, C=6
// bf16 MFMA GEMMs. FP16 residual. Output FLOAT32.
// FINAL = R13 config (best measured 2371us; reproduced 2376us).
// Rejected experiments: R8 BM=128 (2-phase tile too shallow), R10 A-ring
// (latency not binding), R14 lgkm-pipeline (+VGPR pressure), R15 VT BN=128
// (block count up, per-block cost not down), R17 B-ring/1-barrier (null).
// Config: BN=256 QKV/VT/QK, BN=192 PV/FFN2; 2-barrier K-loop; counted vmcnt;
// T1 XCD swizzle; T2 both-sides XOR swizzle; fp16 residual; LDS-bounce epi.
// ---------------------------------------------------------------------------

typedef float f32x4 __attribute__((ext_vector_type(4)));
typedef unsigned short u16x4 __attribute__((ext_vector_type(4)));
typedef unsigned short u16x8 __attribute__((ext_vector_type(8)));
typedef int   i32x4 __attribute__((ext_vector_type(4)));
typedef __bf16 bf16x8 __attribute__((ext_vector_type(8)));

#define NB  32
#define NS  1024
#define ND  768
#define NH  1536
#define NL  4
#define NM  (NB * NS)   // 32768 rows total

__device__ __forceinline__ unsigned short f2bf(float f) {
    unsigned u = __builtin_bit_cast(unsigned, f);
    unsigned r = (u + 0x7FFFu + ((u >> 16) & 1u)) >> 16;   // RNE
    return (unsigned short)r;
}
__device__ __forceinline__ float bf2f(unsigned short h) {
    return __builtin_bit_cast(float, (unsigned)h << 16);
}
__device__ __forceinline__ unsigned short f2h(float f) {
    _Float16 h = (_Float16)f;
    return __builtin_bit_cast(unsigned short, h);
}
__device__ __forceinline__ float h2f(unsigned short u) {
    _Float16 h = __builtin_bit_cast(_Float16, u);
    return (float)h;
}

__device__ __forceinline__ void gl_lds16(const void* g, void* l) {
    __builtin_amdgcn_global_load_lds(
        (const __attribute__((address_space(1))) unsigned int*)g,
        (__attribute__((address_space(3))) unsigned int*)l, 16, 0, 0);
}

// ---------------- embedding -> fp16 residual --------------------------------
__global__ void embed_kernel(const int* __restrict__ tok,
                             const float* __restrict__ emb,
                             const float* __restrict__ pos,
                             unsigned short* __restrict__ x) {
    const int row = blockIdx.x;
    const int c = threadIdx.x;                 // 192 threads, 4 elems each
    const int tk = tok[row];
    const int s = row & (NS - 1);
    f32x4 e = *(const f32x4*)(emb + (size_t)tk * ND + c * 4);
    f32x4 p = *(const f32x4*)(pos + (size_t)s * ND + c * 4);
    u16x4 o;
    #pragma unroll
    for (int i = 0; i < 4; i++) o[i] = f2h(e[i] + p[i]);
    *(u16x4*)(x + (size_t)row * ND + c * 4) = o;
}

// ---------------- weight fp32 [R][C] -> bf16 transposed [C][R], z-strided ---
__global__ __launch_bounds__(256)
void wt_kernel(const float* __restrict__ in, unsigned short* __restrict__ out,
               int R, int Cc, size_t ozs) {
    __shared__ float ls[64][65];
    const int t = threadIdx.x;
    const size_t zi = (size_t)blockIdx.z * R * Cc;
    const size_t zo = (size_t)blockIdx.z * ozs;
    const int r0 = blockIdx.y * 64, c0 = blockIdx.x * 64;
    #pragma unroll
    for (int i = 0; i < 4; i++) {
        const int r = i * 16 + (t >> 4);
        const int c = (t & 15) * 4;
        f32x4 v = *(const f32x4*)(in + zi + (size_t)(r0 + r) * Cc + c0 + c);
        ls[r][c] = v[0]; ls[r][c + 1] = v[1]; ls[r][c + 2] = v[2]; ls[r][c + 3] = v[3];
    }
    __syncthreads();
    #pragma unroll
    for (int i = 0; i < 2; i++) {
        const int c = i * 32 + (t >> 3);
        const int r = (t & 7) * 8;
        u16x8 o;
        #pragma unroll
        for (int j = 0; j < 8; j++) o[j] = f2bf(ls[r + j][c]);
        *(u16x8*)(out + zo + (size_t)(c0 + c) * R + r0 + r) = o;
    }
}

// ---------------- concat bias [bq|bk] per layer -----------------------------
__global__ void bcat_kernel(const float* __restrict__ bq, const float* __restrict__ bk,
                            float* __restrict__ bqk) {
    const int i = blockIdx.x * 256 + threadIdx.x;       // NL*1536
    const int l = i / NH, j = i % NH;
    bqk[i] = (j < ND) ? bq[l * ND + j] : bk[l * ND + j - ND];
}

// ---------------- LayerNorm fp16 in -> bf16 out, one wave per row -----------
__global__ __launch_bounds__(256)
void ln_kernel(const unsigned short* __restrict__ x, const float* __restrict__ g,
               const float* __restrict__ bta, unsigned short* __restrict__ out) {
    const int row = blockIdx.x * 4 + (threadIdx.x >> 6);
    const int l = threadIdx.x & 63;
    const unsigned short* xr = x + (size_t)row * ND;
    f32x4 vv[3];
    float s = 0.f, ss = 0.f;
    #pragma unroll
    for (int j = 0; j < 3; j++) {
        u16x4 hv = *(const u16x4*)(xr + (j * 64 + l) * 4);
        #pragma unroll
        for (int i = 0; i < 4; i++) {
            vv[j][i] = h2f(hv[i]);
            s += vv[j][i]; ss += vv[j][i] * vv[j][i];
        }
    }
    #pragma unroll
    for (int off = 32; off >= 1; off >>= 1) {
        s += __shfl_xor(s, off); ss += __shfl_xor(ss, off);
    }
    const float mean = s * (1.0f / ND);
    const float var = ss * (1.0f / ND) - mean * mean;
    const float rstd = rsqrtf(var + 1e-5f);
    #pragma unroll
    for (int j = 0; j < 3; j++) {
        const int c = (j * 64 + l) * 4;
        f32x4 gv = *(const f32x4*)(g + c);
        f32x4 bv = *(const f32x4*)(bta + c);
        u16x4 o;
        #pragma unroll
        for (int i = 0; i < 4; i++) o[i] = f2bf((vv[j][i] - mean) * rstd * gv[i] + bv[i]);
        *(u16x4*)(out + (size_t)row * ND + c) = o;
    }
}

// ---------------- GEMM 256xBN, 8-phase, 2-barrier: C = A @ Bt^T --------------
// 512 threads = 8 waves (2M x 4N), per-wave 128x(BN/4) out, BK=64.
// LDS: A dbuf 2x32K @0; B dbuf 2x(BN*128) @64K. Stage chunk = 8KB (64 rows).
// Tile: A(t+1)@p0/p1, B(t+2)@p2/p3; mid-tile barrier before p2 staging;
// tile-end barrier + vmcnt(NI). T2 both-sides XOR swizzle.
// EPI: 0 = scale+bias -> bf16; 1 = relu(bias+v) -> bf16; 2 = FP16 C += v
// BROW: bias indexed by output ROW m (for the V^T-producing GEMM).
template<int EPI, int BROW, int BN>
__device__ __forceinline__ void gemm_body(
        const unsigned short* __restrict__ A,
        const unsigned short* __restrict__ Bt,
        const float* __restrict__ bias,
        void* __restrict__ Cv,
        int N, int K, int lda, int ldb,
        long sA, long sB, long sC, float scale, int doswz) {
    constexpr int NI = BN / 64;                // B frags per wave / stage chunks
    constexpr unsigned BBYT = (unsigned)BN * 128u;
    __shared__ __align__(16) unsigned char lds[65536 + 2 * BN * 128];
    const int tid = threadIdx.x;
    const int wid = tid >> 6, l = tid & 63;
    const int wr = wid >> 2, wc = wid & 3;     // wave -> 2x4 grid
    const int fr = l & 15, fq = l >> 4;

    int bn = blockIdx.x, bm = blockIdx.y, bz = blockIdx.z;
    if (doswz) {                               // T1: XCD remap over full grid
        const int gx = gridDim.x, gy = gridDim.y;
        const int nwg = gx * gy * gridDim.z;
        const int flat = (bz * gy + bm) * gx + bn;
        int s = (flat & 7) * (nwg >> 3) + (flat >> 3);
        bn = s % gx; s /= gx; bm = s % gy; bz = s / gy;
    }

    const unsigned short* Ab = A + (size_t)bz * sA + (size_t)(bm * 256) * lda;
    const unsigned short* Bb = Bt + (size_t)bz * sB + (size_t)(bn * BN) * ldb;

    const int srow = tid >> 3;                           // 0..63
    const int scol = ((tid & 7) ^ (srow & 7)) * 8;       // elems (pre-swizzled)
    const unsigned ldst = (unsigned)wid * 1024u;         // wave base (bytes)

    auto stageA = [&](int kt, int h) {                   // 2 insts (128 rows)
        const unsigned base = (unsigned)(kt & 1) * 32768u + (unsigned)h * 16384u;
        #pragma unroll
        for (int li = 0; li < 2; li++)
            gl_lds16(Ab + (size_t)(h * 128 + li * 64 + srow) * lda + (kt * 64 + scol),
                     lds + base + (unsigned)li * 8192u + ldst);
    };
    auto stageB1 = [&](int kt, int li) {                 // 1 inst (64 rows)
        const unsigned base = 65536u + (unsigned)(kt & 1) * BBYT;
        gl_lds16(Bb + (size_t)(li * 64 + srow) * ldb + (kt * 64 + scol),
                 lds + base + (unsigned)li * 8192u + ldst);
    };
    auto ldaf = [&](int buf, int mi, int kk) -> bf16x8 {
        const unsigned r = (unsigned)(wr * 128 + mi * 16 + fr);
        unsigned byt = r * 128u + (unsigned)kk * 64u + (unsigned)fq * 16u;
        byt ^= (r & 7u) << 4;
        return *(const bf16x8*)(lds + (unsigned)buf * 32768u + byt);
    };
    auto ldbf = [&](int buf, int ni, int kk) -> bf16x8 {
        const unsigned r = (unsigned)(wc * (BN / 4) + ni * 16 + fr);
        unsigned byt = r * 128u + (unsigned)kk * 64u + (unsigned)fq * 16u;
        byt ^= (r & 7u) << 4;
        return *(const bf16x8*)(lds + 65536u + (unsigned)buf * BBYT + byt);
    };

    const int NT = K >> 6;
    f32x4 acc[8][NI] = {};

    // ---- prologue: B(0), A(0), B(1); wait so B(0)+A(0) resident -----------
    #pragma unroll
    for (int li = 0; li < NI; li++) stageB1(0, li);
    stageA(0, 0); stageA(0, 1);
    #pragma unroll
    for (int li = 0; li < NI; li++) stageB1(1, li);
    if constexpr (NI == 4)      asm volatile("s_waitcnt vmcnt(4)" ::: "memory");
    else if constexpr (NI == 3) asm volatile("s_waitcnt vmcnt(3)" ::: "memory");
    else                        asm volatile("s_waitcnt vmcnt(2)" ::: "memory");
    __builtin_amdgcn_s_barrier();
    __builtin_amdgcn_sched_barrier(0);

    for (int t = 0; t < NT; ++t) {
        const int cur = t & 1;
        bf16x8 bfr[2 * NI];                    // B-frags, live all 4 phases
        #pragma unroll
        for (int ni = 0; ni < NI; ni++) {
            bfr[ni * 2 + 0] = ldbf(cur, ni, 0);
            bfr[ni * 2 + 1] = ldbf(cur, ni, 1);
        }
        #pragma unroll
        for (int p = 0; p < 4; p++) {
            if (p == 2) {                      // mid-tile barrier: all waves'
                __builtin_amdgcn_s_barrier();  // bfr reads done (their p0
                __builtin_amdgcn_sched_barrier(0); // lgkmcnt(0) executed)
            }
            bf16x8 a0 = ldaf(cur, 2 * p,     0);
            bf16x8 a1 = ldaf(cur, 2 * p,     1);
            bf16x8 a2 = ldaf(cur, 2 * p + 1, 0);
            bf16x8 a3 = ldaf(cur, 2 * p + 1, 1);
            if (p < 2) { if (t + 1 < NT) stageA(t + 1, p); }
            else if (p == 2) {
                if (t + 2 < NT) { stageB1(t + 2, 0); stageB1(t + 2, 1); }
            } else {
                if (t + 2 < NT) {
                    #pragma unroll
                    for (int li = 2; li < NI; li++) stageB1(t + 2, li);
                }
            }
            if (p == 3) {                      // boundary: B(t+2) insts fly
                if (t + 2 < NT) {
                    if constexpr (NI == 4)      asm volatile("s_waitcnt vmcnt(4)" ::: "memory");
                    else if constexpr (NI == 3) asm volatile("s_waitcnt vmcnt(3)" ::: "memory");
                    else                        asm volatile("s_waitcnt vmcnt(2)" ::: "memory");
                } else {
                    asm volatile("s_waitcnt vmcnt(0)" ::: "memory");
                }
            }
            asm volatile("s_waitcnt lgkmcnt(0)" ::: "memory");
            __builtin_amdgcn_sched_barrier(0);
            __builtin_amdgcn_s_setprio(1);
            #pragma unroll
            for (int ni = 0; ni < NI; ni++) {
                acc[2 * p][ni] = __builtin_amdgcn_mfma_f32_16x16x32_bf16(
                    a0, bfr[ni * 2 + 0], acc[2 * p][ni], 0, 0, 0);
                acc[2 * p][ni] = __builtin_amdgcn_mfma_f32_16x16x32_bf16(
                    a1, bfr[ni * 2 + 1], acc[2 * p][ni], 0, 0, 0);
                acc[2 * p + 1][ni] = __builtin_amdgcn_mfma_f32_16x16x32_bf16(
                    a2, bfr[ni * 2 + 0], acc[2 * p + 1][ni], 0, 0, 0);
                acc[2 * p + 1][ni] = __builtin_amdgcn_mfma_f32_16x16x32_bf16(
                    a3, bfr[ni * 2 + 1], acc[2 * p + 1][ni], 0, 0, 0);
            }
            __builtin_amdgcn_s_setprio(0);
            __builtin_amdgcn_sched_barrier(0);
            if (p == 3) {                      // tile-end barrier: all waves'
                __builtin_amdgcn_s_barrier();  // ldaf(cur) reads done (p3
                __builtin_amdgcn_sched_barrier(0); // lgkmcnt(0) executed)
            }
        }
    }

    // ---- epilogue: LDS-bounce, conflict-free read, coalesced stores --------
    constexpr int WS = BN / 4;                  // wave col-span
    constexpr unsigned RST = (unsigned)BN * 4;  // bounce row stride (bytes)
    constexpr int CPR = BN / 64;                // 16-chunk groups per row
    const int erow = tid >> 4;                  // 0..31 (fixed per quarter-wave)
    const int echk = tid & 15;                  // 16B-chunk base within row
    #pragma unroll
    for (int h2 = 0; h2 < 2; ++h2) {
        __builtin_amdgcn_s_barrier();           // K-loop done / prev pass read
        if (wr == h2) {                         // this half's acc -> LDS fp32
            #pragma unroll
            for (int mi = 0; mi < 8; mi++) {
                #pragma unroll
                for (int ni = 0; ni < NI; ni++) {
                    const int nl = wc * WS + ni * 16 + fr;      // block-local col
                    const float bcol = (!BROW && bias) ? bias[bn * BN + nl] : 0.0f;
                    f32x4 brow = {0, 0, 0, 0};
                    if (BROW) brow = *(const f32x4*)(bias + bm * 256 + h2 * 128 + mi * 16 + fq * 4);
                    #pragma unroll
                    for (int r = 0; r < 4; r++) {
                        const int lm = mi * 16 + fq * 4 + r;    // 0..127
                        float v = acc[mi][ni][r] * scale + (BROW ? brow[r] : bcol);
                        if (EPI == 1) v = fmaxf(v, 0.0f);
                        const unsigned byt = ((unsigned)lm * RST + (unsigned)nl * 4u)
                                             ^ ((unsigned)(lm & 7) << 4);
                        *(float*)(lds + byt) = v;
                    }
                }
            }
        }
        __builtin_amdgcn_s_barrier();
        #pragma unroll
        for (int j = 0; j < 4 * CPR; j++) {
            const int row = erow + 32 * (j / CPR);              // 0..127
            const int c   = echk + 16 * (j % CPR);              // chunk idx
            const unsigned byt = ((unsigned)row * RST + (unsigned)c * 16u)
                                 ^ ((unsigned)(row & 7) << 4);
            f32x4 v = *(const f32x4*)(lds + byt);
            const int m = bm * 256 + h2 * 128 + row;
            const int ncol = bn * BN + c * 4;
            const size_t offc = (size_t)bz * sC + (size_t)m * N + ncol;
            if (EPI == 2) {                     // fp16 residual RMW
                unsigned short* cp = (unsigned short*)Cv + offc;
                u16x4 hv = *(const u16x4*)cp;
                u16x4 o;
                #pragma unroll
                for (int r = 0; r < 4; r++) o[r] = f2h(h2f(hv[r]) + v[r]);
                *(u16x4*)cp = o;
            } else {
                u16x4 o;
                o[0] = f2bf(v[0]); o[1] = f2bf(v[1]); o[2] = f2bf(v[2]); o[3] = f2bf(v[3]);
                *(u16x4*)((unsigned short*)Cv + offc) = o;
            }
        }
    }
}

#define GEMM_ARGS const unsigned short* A, const unsigned short* Bt, \
                  const float* bias, void* Cv, int N, int K, int lda, int ldb, \
                  long sA, long sB, long sC, float scale, int doswz
#define GEMM_PASS A, Bt, bias, Cv, N, K, lda, ldb, sA, sB, sC, scale, doswz

// named wrappers for exact rocprof attribution
__global__ __launch_bounds__(512, 2) void gemm_qkv_k (GEMM_ARGS) { gemm_body<0, 0, 256>(GEMM_PASS); }
__global__ __launch_bounds__(512, 2) void gemm_vt_k  (GEMM_ARGS) { gemm_body<0, 1, 256>(GEMM_PASS); }
__global__ __launch_bounds__(512, 2) void gemm_qk_k  (GEMM_ARGS) { gemm_body<0, 0, 256>(GEMM_PASS); }
__global__ __launch_bounds__(512, 2) void gemm_pv_k  (GEMM_ARGS) { gemm_body<2, 0, 192>(GEMM_PASS); }
__global__ __launch_bounds__(512, 2) void gemm_ffn1_k(GEMM_ARGS) { gemm_body<1, 0, 256>(GEMM_PASS); }
__global__ __launch_bounds__(512, 2) void gemm_ffn2_k(GEMM_ARGS) { gemm_body<2, 0, 192>(GEMM_PASS); }

// ---------------- masked softmax (mask from tokens), group-local ------------
__global__ __launch_bounds__(256)
void softmax_kernel(unsigned short* __restrict__ sc, const int* __restrict__ tokg) {
    const int row = blockIdx.x * 4 + (threadIdx.x >> 6);   // row in [0, G*NS)
    const int l = threadIdx.x & 63;
    const int b = row >> 10;                               // batch local to group
    unsigned short* rp = sc + (size_t)row * NS;
    const int* trow = tokg + (size_t)b * NS;
    float v[16];
    float mx = -3.4e38f;
    #pragma unroll
    for (int j = 0; j < 2; j++) {
        u16x8 u = *(const u16x8*)(rp + j * 512 + l * 8);
        i32x4 t0 = *(const i32x4*)(trow + j * 512 + l * 8);
        i32x4 t1 = *(const i32x4*)(trow + j * 512 + l * 8 + 4);
        #pragma unroll
        for (int i = 0; i < 8; i++) {
            const int tk = (i < 4) ? t0[i] : t1[i - 4];
            const float s = (tk == 0) ? -__builtin_inff() : bf2f(u[i]);
            v[j * 8 + i] = s;
            mx = fmaxf(mx, s);
        }
    }
    #pragma unroll
    for (int off = 32; off >= 1; off >>= 1) mx = fmaxf(mx, __shfl_xor(mx, off));
    float sum = 0.f;
    #pragma unroll
    for (int i = 0; i < 16; i++) { v[i] = __expf(v[i] - mx); sum += v[i]; }
    #pragma unroll
    for (int off = 32; off >= 1; off >>= 1) sum += __shfl_xor(sum, off);
    const float inv = 1.0f / sum;
    #pragma unroll
    for (int j = 0; j < 2; j++) {
        u16x8 o;
        #pragma unroll
        for (int i = 0; i < 8; i++) o[i] = f2bf(v[j * 8 + i] * inv);
        *(u16x8*)(rp + j * 512 + l * 8) = o;
    }
}

// ---------------- pool stage 1: partial masked sums over 128-row chunks -----
__global__ __launch_bounds__(256)
void pool1_kernel(const unsigned short* __restrict__ ln,
                  const int* __restrict__ tokg,
                  float* __restrict__ part, float* __restrict__ cnts,
                  int gbase) {                     // gbase: global batch offset
    const int d = blockIdx.x * 256 + threadIdx.x;  // 0..767
    const int b = blockIdx.y;                      // local batch
    const int z = blockIdx.z;                      // seq chunk 0..7
    float s = 0.f, cnt = 0.f;
    const int i0 = z * 128;
    for (int i = i0; i < i0 + 128; i++) {
        const int tk = tokg[b * NS + i];
        if (tk != 0) { s += bf2f(ln[((size_t)b * NS + i) * ND + d]); cnt += 1.0f; }
    }
    part[((size_t)z * NB + (gbase + b)) * ND + d] = s;
    if (d == 0) cnts[z * NB + (gbase + b)] = cnt;
}

// ---------------- pool stage 2: finalize -----------------------------------
__global__ __launch_bounds__(256)
void pool2_kernel(const float* __restrict__ part, const float* __restrict__ cnts,
                  float* __restrict__ pooled) {
    const int d = blockIdx.x * 256 + threadIdx.x;
    const int b = blockIdx.y;                      // global batch
    float s = 0.f, cnt = 0.f;
    #pragma unroll
    for (int z = 0; z < 8; z++) {
        s += part[((size_t)z * NB + b) * ND + d];
        cnt += cnts[z * NB + b];
    }
    pooled[(size_t)b * ND + d] = s / fmaxf(cnt, 1.0f);
}

// ---------------- classifier -> FLOAT32 output ------------------------------
__global__ void cls_kernel(const float* __restrict__ pooled, const float* __restrict__ wc,
                           const float* __restrict__ bc, float* __restrict__ out) {
    const int b = blockIdx.x;
    const int l = threadIdx.x;                  // 64 threads
    float a[6] = {0, 0, 0, 0, 0, 0};
    for (int d = l; d < ND; d += 64) {
        const float p = pooled[b * ND + d];
        #pragma unroll
        for (int c = 0; c < 6; c++) a[c] += p * wc[d * 6 + c];
    }
    #pragma unroll
    for (int c = 0; c < 6; c++) {
        #pragma unroll
        for (int off = 32; off >= 1; off >>= 1) a[c] += __shfl_xor(a[c], off);
    }
    if (l == 0) {
        #pragma unroll
        for (int c = 0; c < 6; c++) out[b * 6 + c] = a[c] + bc[c];
    }
}

__global__ void zero_out_kernel(float* out, int nel) {
    const int i = blockIdx.x * 256 + threadIdx.x;
    if (i < nel) out[i] = 0.0f;
}

// ---------------------------------------------------------------------------
extern "C" void kernel_launch(void* const* d_in, const int* in_sizes, int n_in,
                              void* d_out, int out_size, void* d_ws, size_t ws_size,
                              hipStream_t stream) {
    const int*   tok  = (const int*)d_in[0];
    const float* emb  = (const float*)d_in[1];
    const float* pos  = (const float*)d_in[2];
    const float* ln1w = (const float*)d_in[3];
    const float* ln1b = (const float*)d_in[4];
    const float* ln2w = (const float*)d_in[5];
    const float* ln2b = (const float*)d_in[6];
    const float* wq   = (const float*)d_in[7];
    const float* bq   = (const float*)d_in[8];
    const float* wk   = (const float*)d_in[9];
    const float* bk   = (const float*)d_in[10];
    const float* wv   = (const float*)d_in[11];
    const float* bv   = (const float*)d_in[12];
    const float* w1   = (const float*)d_in[13];
    const float* b1   = (const float*)d_in[14];
    const float* w2   = (const float*)d_in[15];
    const float* b2   = (const float*)d_in[16];
    const float* lnfw = (const float*)d_in[17];
    const float* lnfb = (const float*)d_in[18];
    const float* wcw  = (const float*)d_in[19];
    const float* bcb  = (const float*)d_in[20];
    float* out = (float*)d_out;                 // FLOAT32 output (ref dtype)

    // ---- fixed workspace carve-up ----
    size_t off = 0;
    auto carve = [&](size_t bytes) -> char* {
        char* p = (char*)d_ws + off;
        off += (bytes + 255) & ~(size_t)255;
        return p;
    };
    unsigned short* x = (unsigned short*)carve((size_t)NM * ND * 2);   // fp16 residual
    unsigned short* wqkT = (unsigned short*)carve((size_t)NL * NH * ND * 2); // [l][1536][768]
    unsigned short* wvT  = (unsigned short*)carve((size_t)NL * ND * ND * 2);
    unsigned short* w1T  = (unsigned short*)carve((size_t)NL * ND * NH * 2);
    unsigned short* w2T  = (unsigned short*)carve((size_t)NL * NH * ND * 2);
    float* bqk    = (float*)carve((size_t)NL * NH * 4);
    float* part   = (float*)carve((size_t)8 * NB * ND * 4);
    float* cnts   = (float*)carve((size_t)8 * NB * 4);
    float* pooled = (float*)carve((size_t)NB * ND * 4);

    // ---- adaptive group size ----
    int G = 32;
    while (G >= 1) {
        const size_t pool = (size_t)G *
            ((size_t)NS * ND * 2      // n
           + (size_t)NS * NH * 2      // qk (aliased by h)
           + (size_t)NS * ND * 2      // vt
           + (size_t)NS * NS * 2);    // sc
        if (off + pool <= ws_size) break;
        G >>= 1;
    }
    if (G < 1) {
        zero_out_kernel<<<(out_size + 255) / 256, 256, 0, stream>>>(out, out_size);
        return;
    }
    const int MG = G * NS;                       // rows per group
    unsigned short* n  = (unsigned short*)carve((size_t)MG * ND * 2);
    unsigned short* qk = (unsigned short*)carve((size_t)MG * NH * 2);
    unsigned short* vt = (unsigned short*)carve((size_t)MG * ND * 2); // [b][768][1024]
    unsigned short* sc = (unsigned short*)carve((size_t)G * NS * NS * 2);
    unsigned short* h  = qk;                     // alias: qk dead after scores

    // ---- prepass ----
    embed_kernel<<<NM, 192, 0, stream>>>(tok, emb, pos, x);
    wt_kernel<<<dim3(12, 12, NL), 256, 0, stream>>>(wq, wqkT,            ND, ND, (size_t)NH * ND);
    wt_kernel<<<dim3(12, 12, NL), 256, 0, stream>>>(wk, wqkT + ND * ND,  ND, ND, (size_t)NH * ND);
    wt_kernel<<<dim3(12, 12, NL), 256, 0, stream>>>(wv, wvT,             ND, ND, (size_t)ND * ND);
    wt_kernel<<<dim3(24, 12, NL), 256, 0, stream>>>(w1, w1T,             ND, NH, (size_t)ND * NH);
    wt_kernel<<<dim3(12, 24, NL), 256, 0, stream>>>(w2, w2T,             NH, ND, (size_t)NH * ND);
    bcat_kernel<<<NL * NH / 256, 256, 0, stream>>>(bq, bk, bqk);

    const float iscale = 1.0f / sqrtf((float)ND);
    const int NGroups = NB / G;
    const int MT = MG / 256;                     // 256-row tiles (=4G)
    for (int l = 0; l < NL; l++) {
        for (int g = 0; g < NGroups; g++) {
            const size_t rowoff = (size_t)g * MG;
            unsigned short* xg = x + rowoff * ND;
            ln_kernel<<<MG / 4, 256, 0, stream>>>(xg, ln1w + l * ND, ln1b + l * ND, n);
            // QK fused: qk[MG][1536] = n @ [wq|wk]^T + [bq|bk]   (6,MT)=768
            gemm_qkv_k<<<dim3(6, MT, 1), 512, 0, stream>>>(
                n, wqkT + (size_t)l * NH * ND, bqk + l * NH, qk,
                NH, ND, ND, ND, 0, 0, 0, 1.0f, ((6 * MT) % 8 == 0) ? 1 : 0);
            // V^T direct: vt[b][d][s]  (4,3,G)=384
            gemm_vt_k<<<dim3(4, 3, G), 512, 0, stream>>>(
                wvT + (size_t)l * ND * ND, n, bv + l * ND, vt,
                NS, ND, ND, ND, 0, (long)NS * ND, (long)ND * NS, 1.0f,
                ((12 * G) % 8 == 0) ? 1 : 0);
            // scores = q @ k^T * iscale   (4,4,G)=512
            gemm_qk_k<<<dim3(4, 4, G), 512, 0, stream>>>(
                qk, qk + ND, nullptr, sc,
                NS, ND, NH, NH, (long)NS * NH, (long)NS * NH, (long)NS * NS, iscale,
                ((16 * G) % 8 == 0) ? 1 : 0);
            softmax_kernel<<<MG / 4, 256, 0, stream>>>(sc, tok + rowoff);
            // x += attn @ V   (BN=192: (4,4,G)=512 = 2.0 rounds)
            gemm_pv_k<<<dim3(4, 4, G), 512, 0, stream>>>(
                sc, vt, nullptr, xg,
                ND, NS, NS, NS, (long)NS * NS, (long)ND * NS, (long)NS * ND, 1.0f,
                ((16 * G) % 8 == 0) ? 1 : 0);
            ln_kernel<<<MG / 4, 256, 0, stream>>>(xg, ln2w + l * ND, ln2b + l * ND, n);
            // FFN1 (6,MT)=768
            gemm_ffn1_k<<<dim3(6, MT, 1), 512, 0, stream>>>(
                n, w1T + (size_t)l * ND * NH, b1 + l * NH, h,
                NH, ND, ND, ND, 0, 0, 0, 1.0f, ((6 * MT) % 8 == 0) ? 1 : 0);
            // FFN2 (BN=192: (4,MT)=512 = 2.0 rounds)
            gemm_ffn2_k<<<dim3(4, MT, 1), 512, 0, stream>>>(
                h, w2T + (size_t)l * ND * NH, b2 + l * ND, xg,
                ND, NH, NH, NH, 0, 0, 0, 1.0f, ((4 * MT) % 8 == 0) ? 1 : 0);
        }
    }
    for (int g = 0; g < NGroups; g++) {
        const size_t rowoff = (size_t)g * MG;
        ln_kernel<<<MG / 4, 256, 0, stream>>>(x + rowoff * ND, lnfw, lnfb, n);
        pool1_kernel<<<dim3(3, G, 8), 256, 0, stream>>>(n, tok + rowoff, part, cnts, g * G);
    }
    pool2_kernel<<<dim3(3, NB), 256, 0, stream>>>(part, cnts, pooled);
    cls_kernel<<<NB, 64, 0, stream>>>(pooled, wcw, bcb, out);
}